// Round 5
// baseline (58.082 us; speedup 1.0000x reference)
//
#include <hip/hip_runtime.h>
#include <hip/hip_bf16.h>
#include <math.h>

// HOG forward: im (16,3,512,512) f32 -> (16,1,31,31,2,2,9) f32
// CELL=16, BLOCK=2, NBINS=9; Hc=Wc=32, Hb=Wb=31, P=256

#define IMG_H 512
#define IMG_W 512
#define NCH 3
#define NB_ 16
#define HC 32
#define WC 32
#define HB 31
#define WB 31
#define NBINS 9

__device__ __forceinline__ int refl(int i, int n) {
    if (i < 0) i = -i;
    else if (i >= n) i = 2 * n - 2 - i;
    return i;
}

// Register-tile HOG histogram: NO LDS, NO barriers.
// Grid: 16 img x 8 tile-rows x 8 tile-cols (1024 blocks), 256 threads.
// Thread: 4 cols (float4-aligned) x 4 rows = 16 px.
// Wave = one cell-row (4 cells x 16 lanes); in-wave butterfly reduce.
__global__ __launch_bounds__(256, 4) void hog_hist_kernel(const float* __restrict__ im,
                                                          float* __restrict__ hist) {
    const int bid = blockIdx.x;            // ((b*8 + tr)*8 + tc)
    const int b  = bid >> 6;
    const int tr = (bid >> 3) & 7;
    const int tc = bid & 7;

    const int t  = threadIdx.x;
    const int cg = t & 15;                 // col group (0..15)
    const int rg = t >> 4;                 // row group (0..15)

    const int y0 = tr * 64 + rg * 4;       // first px row of this thread
    const int x0 = tc * 64 + cg * 4;       // first px col (float4-aligned)

    const float* imb = im + (size_t)b * NCH * IMG_H * IMG_W;

    // window rows y0-1 .. y0+4 (reflect), as precomputed row offsets
    int yoff[6];
#pragma unroll
    for (int j = 0; j < 6; ++j) yoff[j] = refl(y0 - 1 + j, IMG_H) * IMG_W;
    const int xl = (x0 == 0) ? 1 : x0 - 1;             // refl(x0-1)
    const int xr = (x0 + 4 >= IMG_W) ? IMG_W - 2 : x0 + 4; // refl(x0+4)

    float bn[16], bgx[16], bgy[16];
#pragma unroll
    for (int p = 0; p < 16; ++p) { bn[p] = -1.0f; bgx[p] = 0.0f; bgy[p] = 0.0f; }

#pragma unroll
    for (int c = 0; c < NCH; ++c) {
        const float* chp = imb + (size_t)c * (IMG_H * IMG_W);
        float w[6][6];
#pragma unroll
        for (int j = 0; j < 6; ++j) {
            const float* rp = chp + yoff[j];
            const float4 v = *(const float4*)(rp + x0);
            w[j][0] = rp[xl];
            w[j][1] = v.x; w[j][2] = v.y; w[j][3] = v.z; w[j][4] = v.w;
            w[j][5] = rp[xr];
        }
#pragma unroll
        for (int p = 0; p < 4; ++p) {
#pragma unroll
            for (int q = 0; q < 4; ++q) {
                const int ix = p * 4 + q;
                // identical association to the verified kernel:
                float gx = ((w[p][q + 2] - w[p][q]) + 2.0f * (w[p + 1][q + 2] - w[p + 1][q]))
                         + (w[p + 2][q + 2] - w[p + 2][q]);
                float gy = ((w[p + 2][q] - w[p][q]) + 2.0f * (w[p + 2][q + 1] - w[p][q + 1]))
                         + (w[p + 2][q + 2] - w[p][q + 2]);
                float n = sqrtf(gx * gx + gy * gy);
                if (n > bn[ix]) { bn[ix] = n; bgx[ix] = gx; bgy[ix] = gy; }
            }
        }
    }

    const float PI_F  = (float)M_PI;
    const float HPI_F = (float)(M_PI / 2.0);
    const float GAIN  = (float)(9.0 / M_PI);
    // minimax odd poly for atan on [0,1], max err ~2e-5 rad
    const float C1  = 0.99997726f, C3 = -0.33262347f, C5 = 0.19354346f;
    const float C7  = -0.11643287f, C9 = 0.05265332f, C11 = -0.01172120f;

    float acc[NBINS];
#pragma unroll
    for (int k = 0; k < NBINS; ++k) acc[k] = 0.0f;

#pragma unroll
    for (int p = 0; p < 16; ++p) {
        float gx = bgx[p], gy = bgy[p], n = bn[p];
        float ax = fabsf(gx), ay = fabsf(gy);
        float mn = fminf(ax, ay), mx = fmaxf(ax, ay);
        float r  = __fdividef(mn, mx + 1e-37f);
        float r2 = r * r;
        float at = r * (C1 + r2 * (C3 + r2 * (C5 + r2 * (C7 + r2 * (C9 + r2 * C11)))));
        if (ay > ax) at = HPI_F - at;
        if ((__float_as_uint(gx) ^ __float_as_uint(gy)) & 0x80000000u) at = PI_F - at;
        // at = atan2(gy,gx) mod pi, in [0, pi]
        float fp = GAIN * at;              // [0, 9]

        // tent binning: bin k gets n * max(0, 1-|fp-k|); bin 0 wraps at 9
        float w0 = fmaxf(1.0f - fabsf(fp), 0.0f) + fmaxf(1.0f - fabsf(fp - 9.0f), 0.0f);
        acc[0] = fmaf(w0, n, acc[0]);
#pragma unroll
        for (int k = 1; k < NBINS; ++k) {
            float wk = fmaxf(1.0f - fabsf(fp - (float)k), 0.0f);
            acc[k] = fmaf(wk, n, acc[k]);
        }
    }

    // in-wave butterfly over the cell's 16 lanes: col bits (1,2) + row bits (16,32)
#pragma unroll
    for (int k = 0; k < NBINS; ++k) acc[k] += __shfl_xor(acc[k], 1, 64);
#pragma unroll
    for (int k = 0; k < NBINS; ++k) acc[k] += __shfl_xor(acc[k], 2, 64);
#pragma unroll
    for (int k = 0; k < NBINS; ++k) acc[k] += __shfl_xor(acc[k], 16, 64);
#pragma unroll
    for (int k = 0; k < NBINS; ++k) acc[k] += __shfl_xor(acc[k], 32, 64);

    const int lane = t & 63;
    const int kk = lane & 3;
    const int cj = (lane >> 2) & 3;
    const int r4 = (lane >> 4) & 3;
    const int lid = r4 * 4 + kk;           // 0..15; first 9 write bins
    if (lid < NBINS) {
        float outv = 0.0f;
#pragma unroll
        for (int z = 0; z < NBINS; ++z) outv = (lid == z) ? acc[z] : outv;  // static idx
        const int wv = t >> 6;
        const int cellY = tr * 4 + wv;
        const int cellX = tc * 4 + cj;
        size_t cell = ((size_t)b * HC + cellY) * WC + cellX;
        hist[cell * NBINS + lid] = outv * (1.0f / 256.0f);
    }
}

// One thread per output block: gather 2x2 cells x 9 bins, L2-Hys normalize.
__global__ __launch_bounds__(256) void hog_norm_kernel(const float* __restrict__ hist,
                                                       float* __restrict__ out) {
    int idx = blockIdx.x * 256 + threadIdx.x;  // b*961 + i*31 + j
    if (idx >= NB_ * HB * WB) return;
    int b = idx / (HB * WB);
    int r = idx - b * (HB * WB);
    int i = r / WB;
    int j = r - i * WB;

    float v[36];
    float ss = 0.0f;
#pragma unroll
    for (int bi = 0; bi < 2; ++bi) {
#pragma unroll
        for (int bj = 0; bj < 2; ++bj) {
            const float* hp = hist + (size_t)(((b * HC) + (i + bi)) * WC + (j + bj)) * NBINS;
#pragma unroll
            for (int k = 0; k < NBINS; ++k) {
                float x = hp[k];
                v[(bi * 2 + bj) * NBINS + k] = x;
                ss += x * x;
            }
        }
    }
    float inv1 = 1.0f / (sqrtf(ss) + 1e-10f);
    float ss2 = 0.0f;
#pragma unroll
    for (int k = 0; k < 36; ++k) {
        float tt = fminf(v[k] * inv1, 0.2f);
        v[k] = tt;
        ss2 += tt * tt;
    }
    float inv2 = 1.0f / (sqrtf(ss2) + 1e-10f);
    float* op = out + (size_t)idx * 36;
#pragma unroll
    for (int k = 0; k < 36; ++k) op[k] = v[k] * inv2;
}

extern "C" void kernel_launch(void* const* d_in, const int* in_sizes, int n_in,
                              void* d_out, int out_size, void* d_ws, size_t ws_size,
                              hipStream_t stream) {
    const float* im = (const float*)d_in[0];
    float* out = (float*)d_out;
    float* hist = (float*)d_ws;  // 16*32*32*9 floats = 589,824 bytes

    hog_hist_kernel<<<NB_ * 8 * 8, 256, 0, stream>>>(im, hist);

    int nout_blocks = NB_ * HB * WB;           // 15376
    hog_norm_kernel<<<(nout_blocks + 255) / 256, 256, 0, stream>>>(hist, out);
}

// Round 6
// 35.388 us; speedup vs baseline: 1.6413x; 1.6413x over previous
//
#include <hip/hip_runtime.h>
#include <hip/hip_bf16.h>
#include <math.h>

// HOG forward: im (16,3,512,512) f32 -> (16,1,31,31,2,2,9) f32
// CELL=16, BLOCK=2, NBINS=9; Hc=Wc=32, Hb=Wb=31, P=256

#define IMG_H 512
#define IMG_W 512
#define NCH 3
#define NB_ 16
#define HC 32
#define WC 32
#define HB 31
#define WB 31
#define NBINS 9

__device__ __forceinline__ int refl(int i, int n) {
    if (i < 0) i = -i;
    else if (i >= n) i = 2 * n - 2 - i;
    return i;
}

// Register-tile HOG histogram: NO LDS, NO barriers, no forced VGPR cap.
// Grid: 16 img x 8 tile-rows x 8 tile-cols (1024 blocks), 256 threads.
// Thread: 4 cols (float4-aligned) x 4 rows = 16 px.
// Wave = one cell-row (4 cells x 16 lanes); in-wave butterfly reduce.
__global__ __launch_bounds__(256) void hog_hist_kernel(const float* __restrict__ im,
                                                       float* __restrict__ hist) {
    const int bid = blockIdx.x;            // ((b*8 + tr)*8 + tc)
    const int b  = bid >> 6;
    const int tr = (bid >> 3) & 7;
    const int tc = bid & 7;

    const int t  = threadIdx.x;
    const int cg = t & 15;                 // col group (0..15)
    const int rg = t >> 4;                 // row group (0..15)

    const int y0 = tr * 64 + rg * 4;       // first px row of this thread
    const int x0 = tc * 64 + cg * 4;       // first px col (float4-aligned)

    const float* imb = im + (size_t)b * NCH * IMG_H * IMG_W;

    // window rows y0-1 .. y0+4 (reflect), as precomputed row offsets
    int yoff[6];
#pragma unroll
    for (int j = 0; j < 6; ++j) yoff[j] = refl(y0 - 1 + j, IMG_H) * IMG_W;
    const int xl = (x0 == 0) ? 1 : x0 - 1;             // refl(x0-1)
    const int xr = (x0 + 4 >= IMG_W) ? IMG_W - 2 : x0 + 4; // refl(x0+4)

    float bn[16], bgx[16], bgy[16];
#pragma unroll
    for (int p = 0; p < 16; ++p) { bn[p] = -1.0f; bgx[p] = 0.0f; bgy[p] = 0.0f; }

#pragma unroll
    for (int c = 0; c < NCH; ++c) {
        const float* chp = imb + (size_t)c * (IMG_H * IMG_W);
        float w[6][6];
#pragma unroll
        for (int j = 0; j < 6; ++j) {
            const float* rp = chp + yoff[j];
            const float4 v = *(const float4*)(rp + x0);
            w[j][0] = rp[xl];
            w[j][1] = v.x; w[j][2] = v.y; w[j][3] = v.z; w[j][4] = v.w;
            w[j][5] = rp[xr];
        }
#pragma unroll
        for (int p = 0; p < 4; ++p) {
#pragma unroll
            for (int q = 0; q < 4; ++q) {
                const int ix = p * 4 + q;
                // identical association to the verified kernel:
                float gx = ((w[p][q + 2] - w[p][q]) + 2.0f * (w[p + 1][q + 2] - w[p + 1][q]))
                         + (w[p + 2][q + 2] - w[p + 2][q]);
                float gy = ((w[p + 2][q] - w[p][q]) + 2.0f * (w[p + 2][q + 1] - w[p][q + 1]))
                         + (w[p + 2][q + 2] - w[p][q + 2]);
                float n = sqrtf(gx * gx + gy * gy);
                if (n > bn[ix]) { bn[ix] = n; bgx[ix] = gx; bgy[ix] = gy; }
            }
        }
    }

    const float PI_F  = (float)M_PI;
    const float HPI_F = (float)(M_PI / 2.0);
    const float GAIN  = (float)(9.0 / M_PI);
    // minimax odd poly for atan on [0,1], max err ~2e-5 rad
    const float C1  = 0.99997726f, C3 = -0.33262347f, C5 = 0.19354346f;
    const float C7  = -0.11643287f, C9 = 0.05265332f, C11 = -0.01172120f;

    float acc[NBINS];
#pragma unroll
    for (int k = 0; k < NBINS; ++k) acc[k] = 0.0f;

#pragma unroll
    for (int p = 0; p < 16; ++p) {
        float gx = bgx[p], gy = bgy[p], n = bn[p];
        float ax = fabsf(gx), ay = fabsf(gy);
        float mn = fminf(ax, ay), mx = fmaxf(ax, ay);
        float r  = __fdividef(mn, mx + 1e-37f);
        float r2 = r * r;
        float at = r * (C1 + r2 * (C3 + r2 * (C5 + r2 * (C7 + r2 * (C9 + r2 * C11)))));
        if (ay > ax) at = HPI_F - at;
        if ((__float_as_uint(gx) ^ __float_as_uint(gy)) & 0x80000000u) at = PI_F - at;
        // at = atan2(gy,gx) mod pi, in [0, pi]
        float fp = GAIN * at;              // [0, 9]

        // tent binning: bin k gets n * max(0, 1-|fp-k|); bin 0 wraps at 9
        float w0 = fmaxf(1.0f - fabsf(fp), 0.0f) + fmaxf(1.0f - fabsf(fp - 9.0f), 0.0f);
        acc[0] = fmaf(w0, n, acc[0]);
#pragma unroll
        for (int k = 1; k < NBINS; ++k) {
            float wk = fmaxf(1.0f - fabsf(fp - (float)k), 0.0f);
            acc[k] = fmaf(wk, n, acc[k]);
        }
    }

    // in-wave butterfly over the cell's 16 lanes: col bits (1,2) + row bits (16,32)
#pragma unroll
    for (int k = 0; k < NBINS; ++k) acc[k] += __shfl_xor(acc[k], 1, 64);
#pragma unroll
    for (int k = 0; k < NBINS; ++k) acc[k] += __shfl_xor(acc[k], 2, 64);
#pragma unroll
    for (int k = 0; k < NBINS; ++k) acc[k] += __shfl_xor(acc[k], 16, 64);
#pragma unroll
    for (int k = 0; k < NBINS; ++k) acc[k] += __shfl_xor(acc[k], 32, 64);

    const int lane = t & 63;
    const int kk = lane & 3;
    const int cj = (lane >> 2) & 3;
    const int r4 = (lane >> 4) & 3;
    const int lid = r4 * 4 + kk;           // 0..15; first 9 write bins
    if (lid < NBINS) {
        float outv = 0.0f;
#pragma unroll
        for (int z = 0; z < NBINS; ++z) outv = (lid == z) ? acc[z] : outv;  // static idx
        const int wv = t >> 6;
        const int cellY = tr * 4 + wv;
        const int cellX = tc * 4 + cj;
        size_t cell = ((size_t)b * HC + cellY) * WC + cellX;
        hist[cell * NBINS + lid] = outv * (1.0f / 256.0f);
    }
}

// One thread per output block: gather 2x2 cells x 9 bins, L2-Hys normalize.
__global__ __launch_bounds__(256) void hog_norm_kernel(const float* __restrict__ hist,
                                                       float* __restrict__ out) {
    int idx = blockIdx.x * 256 + threadIdx.x;  // b*961 + i*31 + j
    if (idx >= NB_ * HB * WB) return;
    int b = idx / (HB * WB);
    int r = idx - b * (HB * WB);
    int i = r / WB;
    int j = r - i * WB;

    float v[36];
    float ss = 0.0f;
#pragma unroll
    for (int bi = 0; bi < 2; ++bi) {
#pragma unroll
        for (int bj = 0; bj < 2; ++bj) {
            const float* hp = hist + (size_t)(((b * HC) + (i + bi)) * WC + (j + bj)) * NBINS;
#pragma unroll
            for (int k = 0; k < NBINS; ++k) {
                float x = hp[k];
                v[(bi * 2 + bj) * NBINS + k] = x;
                ss += x * x;
            }
        }
    }
    float inv1 = 1.0f / (sqrtf(ss) + 1e-10f);
    float ss2 = 0.0f;
#pragma unroll
    for (int k = 0; k < 36; ++k) {
        float tt = fminf(v[k] * inv1, 0.2f);
        v[k] = tt;
        ss2 += tt * tt;
    }
    float inv2 = 1.0f / (sqrtf(ss2) + 1e-10f);
    float* op = out + (size_t)idx * 36;
#pragma unroll
    for (int k = 0; k < 36; ++k) op[k] = v[k] * inv2;
}

extern "C" void kernel_launch(void* const* d_in, const int* in_sizes, int n_in,
                              void* d_out, int out_size, void* d_ws, size_t ws_size,
                              hipStream_t stream) {
    const float* im = (const float*)d_in[0];
    float* out = (float*)d_out;
    float* hist = (float*)d_ws;  // 16*32*32*9 floats = 589,824 bytes

    hog_hist_kernel<<<NB_ * 8 * 8, 256, 0, stream>>>(im, hist);

    int nout_blocks = NB_ * HB * WB;           // 15376
    hog_norm_kernel<<<(nout_blocks + 255) / 256, 256, 0, stream>>>(hist, out);
}